// Round 14
// baseline (816.092 us; speedup 1.0000x reference)
//
#include <hip/hip_runtime.h>
#include <math.h>

#define D_MODEL 1024
#define D_INNER 2048
#define D_STATE 16
#define D_CONV  4
#define NCHUNK  32
#define LCHUNK  32

typedef unsigned short u16;
typedef __attribute__((ext_vector_type(8))) short short8;
typedef __attribute__((ext_vector_type(4))) float f32x4;
typedef __attribute__((ext_vector_type(4))) unsigned short u16x4;
typedef __attribute__((ext_vector_type(8))) unsigned short u16x8;

__device__ __forceinline__ float silu_f(float x) { return x / (1.f + __expf(-x)); }
__device__ __forceinline__ float softplus_f(float x) {
    return fmaxf(x, 0.f) + log1pf(__expf(-fabsf(x)));
}
__device__ __forceinline__ u16 f2bf(float f) {
    union { float f; unsigned u; } c; c.f = f;
    unsigned r = c.u + 0x7fffu + ((c.u >> 16) & 1u);   // RNE
    return (u16)(r >> 16);
}
__device__ __forceinline__ float bf2f(u16 v) {
    union { unsigned u; float f; } c; c.u = ((unsigned)v) << 16; return c.f;
}
__device__ __forceinline__ void gload_lds16(const void* g, void* l) {
    __builtin_amdgcn_global_load_lds((const __attribute__((address_space(1))) void*)g,
                                     (__attribute__((address_space(3))) void*)l, 16, 0, 0);
}

// ---------------------------------------------------------------------------
// fp32 -> bf16 elementwise convert
// ---------------------------------------------------------------------------
__global__ __launch_bounds__(256)
void f32_to_bf16_kernel(const float* __restrict__ in, u16* __restrict__ out, int n4)
{
    const int i = blockIdx.x * 256 + threadIdx.x;
    if (i >= n4) return;
    const float4 v = *(const float4*)&in[(size_t)i * 4];
    u16x4 o; o.x = f2bf(v.x); o.y = f2bf(v.y); o.z = f2bf(v.z); o.w = f2bf(v.w);
    *(u16x4*)&out[(size_t)i * 4] = o;
}

// ---------------------------------------------------------------------------
// W[K][N] fp32 -> Wt[N][K] bf16 (32x32 LDS tiles)
// ---------------------------------------------------------------------------
__global__ __launch_bounds__(256)
void transpose_bf16_kernel(const float* __restrict__ W, u16* __restrict__ Wt, int K, int N)
{
    __shared__ float tile[32][33];
    const int tx = threadIdx.x & 31, ty = threadIdx.x >> 5;
    const int n0 = blockIdx.x * 32, k0 = blockIdx.y * 32;
#pragma unroll
    for (int q = 0; q < 4; q++)
        tile[ty + q * 8][tx] = W[(size_t)(k0 + ty + q * 8) * N + n0 + tx];
    __syncthreads();
#pragma unroll
    for (int q = 0; q < 4; q++)
        Wt[(size_t)(n0 + ty + q * 8) * K + k0 + tx] = f2bf(tile[tx][ty + q * 8]);
}

// ---------------------------------------------------------------------------
// 256x256 bf16 MFMA GEMM — 8-phase schedule (R12 schedule, spill-proof
// codegen: named fragment vars, zero loops in hot path, literal acc indices,
// launch_bounds (512,2) matching the proven gemm_mfma256 register regime).
// 8 waves (2M x 4N), BK=64, per-wave 128x64. Schedule validated correct
// in R12 (absmax unchanged); per-phase: {ds-load named frags; stage
// half-tile(s); [vmcnt(4) @ ph4/ph8]; barrier; lgkmcnt(0)+sched_barrier;
// setprio(1); 16 explicit MFMA; setprio(0); barrier}.
// MODE 0: col<D_INNER -> out0(u16)=bf16(silu); else out1(u16)=bf16(v)
// MODE 1: out0(u16) = bf16(softplus(v))
// ---------------------------------------------------------------------------
template <int MODE>
__global__ __launch_bounds__(512, 2)
void gemm_8ph(const u16* __restrict__ A, const u16* __restrict__ Bt,
              const float* __restrict__ bias,
              void* __restrict__ out0v, void* __restrict__ out1v,
              int M, int N, int K)
{
    __shared__ __align__(16) short As[2][16384];   // 64 KB
    __shared__ __align__(16) short Bs[2][16384];   // 64 KB

    const int tid = threadIdx.x;
    const int wid = tid >> 6, lane = tid & 63;
    const int wr = wid >> 2, wc = wid & 3;          // 2M x 4N waves
    const int kg = lane >> 4, r16 = lane & 15;
    const int rx = r16 & 7;
    const int s0 = ((kg) ^ rx) << 3;                // ks0 swizzled slot (elements)
    const int s1 = ((4 + kg) ^ rx) << 3;            // ks1 swizzled slot

    // XCD-bijective block swizzle (nwg % 8 == 0 for our grids)
    int lb = blockIdx.y * gridDim.x + blockIdx.x;
    const int nwg = gridDim.x * gridDim.y;
    lb = (lb & 7) * (nwg >> 3) + (lb >> 3);
    const int bx = lb % gridDim.x, by = lb / gridDim.x;
    const int row0 = by * 256, col0 = bx * 256;

    f32x4 acc[8][4] = {};
    const u16* Abase = A + (size_t)row0 * K;
    const u16* Bbase = Bt + (size_t)col0 * K;

    short8 a00, a01, a02, a03;   // ks0 frag rows of current mh
    short8 a10, a11, a12, a13;   // ks1
    short8 b00, b01;             // ks0 frag cols of current nh
    short8 b10, b11;             // ks1

// stage one 128-row half-tile: 2 gloads/thread, explicit halves.
#define STA(BI, MH, KK) do {                                                        \
    { const int c_ = tid;       const int r_ = c_ >> 3;                             \
      gload_lds16(Abase + (size_t)((MH) * 128 + r_) * K + (KK) + (((c_ & 7) ^ (r_ & 7)) << 3), \
                  &As[BI][(((MH) << 10) + (wid << 6)) << 3]); }                     \
    { const int c_ = 512 + tid; const int r_ = c_ >> 3;                             \
      gload_lds16(Abase + (size_t)((MH) * 128 + r_) * K + (KK) + (((c_ & 7) ^ (r_ & 7)) << 3), \
                  &As[BI][(((MH) << 10) + (1 << 9) + (wid << 6)) << 3]); }          \
} while (0)
#define STB(BI, MH, KK) do {                                                        \
    { const int c_ = tid;       const int r_ = c_ >> 3;                             \
      gload_lds16(Bbase + (size_t)((MH) * 128 + r_) * K + (KK) + (((c_ & 7) ^ (r_ & 7)) << 3), \
                  &Bs[BI][(((MH) << 10) + (wid << 6)) << 3]); }                     \
    { const int c_ = 512 + tid; const int r_ = c_ >> 3;                             \
      gload_lds16(Bbase + (size_t)((MH) * 128 + r_) * K + (KK) + (((c_ & 7) ^ (r_ & 7)) << 3), \
                  &Bs[BI][(((MH) << 10) + (1 << 9) + (wid << 6)) << 3]); }          \
} while (0)

// ds-load named A fragments for half MH from buffer BI (8 x ds_read_b128)
#define LDA(BI, MH) do {                                                            \
    const short* _p = &As[BI][(wr * 128 + (MH) * 64 + r16) * 64];                   \
    a00 = *(const short8*)&_p[0    + s0];  a10 = *(const short8*)&_p[0    + s1];    \
    a01 = *(const short8*)&_p[1024 + s0];  a11 = *(const short8*)&_p[1024 + s1];    \
    a02 = *(const short8*)&_p[2048 + s0];  a12 = *(const short8*)&_p[2048 + s1];    \
    a03 = *(const short8*)&_p[3072 + s0];  a13 = *(const short8*)&_p[3072 + s1];    \
} while (0)
// ds-load named B fragments for half NH from buffer BI (4 x ds_read_b128)
#define LDB(BI, NH) do {                                                            \
    const short* _q = &Bs[BI][(wc * 64 + (NH) * 32 + r16) * 64];                    \
    b00 = *(const short8*)&_q[0    + s0];  b10 = *(const short8*)&_q[0    + s1];    \
    b01 = *(const short8*)&_q[1024 + s0];  b11 = *(const short8*)&_q[1024 + s1];    \
} while (0)

#define MF(CI, CJ, AV, BV) acc[CI][CJ] = __builtin_amdgcn_mfma_f32_16x16x32_bf16(AV, BV, acc[CI][CJ], 0, 0, 0)
// 16 explicit MFMAs for C-quadrant (MH, NH); all acc indices literal.
#define QUAD(MH, NH) do {                                                           \
    MF((MH)*4+0, (NH)*2+0, a00, b00); MF((MH)*4+0, (NH)*2+1, a00, b01);             \
    MF((MH)*4+1, (NH)*2+0, a01, b00); MF((MH)*4+1, (NH)*2+1, a01, b01);             \
    MF((MH)*4+2, (NH)*2+0, a02, b00); MF((MH)*4+2, (NH)*2+1, a02, b01);             \
    MF((MH)*4+3, (NH)*2+0, a03, b00); MF((MH)*4+3, (NH)*2+1, a03, b01);             \
    MF((MH)*4+0, (NH)*2+0, a10, b10); MF((MH)*4+0, (NH)*2+1, a10, b11);             \
    MF((MH)*4+1, (NH)*2+0, a11, b10); MF((MH)*4+1, (NH)*2+1, a11, b11);             \
    MF((MH)*4+2, (NH)*2+0, a12, b10); MF((MH)*4+2, (NH)*2+1, a12, b11);             \
    MF((MH)*4+3, (NH)*2+0, a13, b10); MF((MH)*4+3, (NH)*2+1, a13, b11);             \
} while (0)

#define PH_SYNC do { __builtin_amdgcn_s_barrier();                                  \
    asm volatile("s_waitcnt lgkmcnt(0)" ::: "memory");                              \
    __builtin_amdgcn_sched_barrier(0); } while (0)
#define PRIO1 __builtin_amdgcn_s_setprio(1)
#define PRIO0 __builtin_amdgcn_s_setprio(0)
#define ENDBAR __builtin_amdgcn_s_barrier()
#define VMC4 asm volatile("s_waitcnt vmcnt(4)" ::: "memory")

    const int ntile = K >> 6;
    // prologue: A[0] h0/h1, B[0] h0/h1, B[1] h0/h1 (12 loads)
    STA(0, 0, 0); STA(0, 1, 0);
    STB(0, 0, 0); STB(0, 1, 0);
    STB(1, 0, 64); STB(1, 1, 64);
    VMC4;                       // A[0], B[0] landed; B[1] (4) in flight
    __builtin_amdgcn_s_barrier();

    for (int T = 0; T < ntile; T += 2) {
        const int kA1 = (T + 1) << 6;
        const int kN2 = ((T + 2) & (ntile - 1)) << 6;   // wraps at tail (harmless)
        const int kN3 = ((T + 3) & (ntile - 1)) << 6;
        // ph1: buf0 quadrant (mh0, nh0)
        LDA(0, 0); LDB(0, 0);
        STA(1, 0, kA1);
        PH_SYNC; PRIO1; QUAD(0, 0); PRIO0; ENDBAR;
        // ph2: (mh1, nh0) — reuse b
        LDA(0, 1);
        STA(1, 1, kA1);
        PH_SYNC; PRIO1; QUAD(1, 0); PRIO0; ENDBAR;
        // ph3: (mh1, nh1) — reuse a
        LDB(0, 1);
        PH_SYNC; PRIO1; QUAD(1, 1); PRIO0; ENDBAR;
        // ph4: (mh0, nh1) — reuse b; stage B[T+2]; drain A[T+1] (+older)
        LDA(0, 0);
        STB(0, 0, kN2); STB(0, 1, kN2);
        VMC4;
        PH_SYNC; PRIO1; QUAD(0, 1); PRIO0; ENDBAR;
        // ph5: buf1 quadrant (mh0, nh0)
        LDA(1, 0); LDB(1, 0);
        STA(0, 0, kN2);
        PH_SYNC; PRIO1; QUAD(0, 0); PRIO0; ENDBAR;
        // ph6: (mh1, nh0)
        LDA(1, 1);
        STA(0, 1, kN2);
        PH_SYNC; PRIO1; QUAD(1, 0); PRIO0; ENDBAR;
        // ph7: (mh1, nh1)
        LDB(1, 1);
        PH_SYNC; PRIO1; QUAD(1, 1); PRIO0; ENDBAR;
        // ph8: (mh0, nh1); stage B[T+3]; drain B[T+2]+A[T+2]
        LDA(1, 0);
        STB(1, 0, kN3); STB(1, 1, kN3);
        VMC4;
        PH_SYNC; PRIO1; QUAD(0, 1); PRIO0; ENDBAR;
    }
#undef STA
#undef STB
#undef LDA
#undef LDB
#undef MF
#undef QUAD
#undef PH_SYNC
#undef PRIO1
#undef PRIO0
#undef ENDBAR
#undef VMC4

    // epilogue: D frag layout col = lane&15, row = (lane>>4)*4 + reg
#pragma unroll
    for (int i = 0; i < 8; i++) {
#pragma unroll
        for (int j = 0; j < 4; j++) {
#pragma unroll
            for (int r = 0; r < 4; r++) {
                const int row = row0 + wr * 128 + i * 16 + kg * 4 + r;
                const int col = col0 + wc * 64 + j * 16 + r16;
                const float v = acc[i][j][r] + bias[col];
                if (MODE == 0) {
                    u16* o0 = (u16*)out0v; u16* o1 = (u16*)out1v;
                    if (col < D_INNER) o0[(size_t)row * D_INNER + col] = f2bf(silu_f(v));
                    else               o1[(size_t)row * D_INNER + (col - D_INNER)] = f2bf(v);
                } else {
                    ((u16*)out0v)[(size_t)row * N + col] = f2bf(softplus_f(v));
                }
            }
        }
    }
}

// ---------------------------------------------------------------------------
// 128x128 bf16 MFMA GEMM (proven): triple-buffered, counted vmcnt.
// out0(f32) = v + aux (out_proj + residual).
// ---------------------------------------------------------------------------
__global__ __launch_bounds__(256)
void gemm_mfma_128(const u16* __restrict__ A, const u16* __restrict__ Bt,
                   const float* __restrict__ bias, const float* __restrict__ aux,
                   float* __restrict__ out0, int M, int N, int K)
{
    __shared__ __align__(16) short As[3][4096];
    __shared__ __align__(16) short Bs[3][4096];

    const int tid = threadIdx.x;
    const int wid = tid >> 6, lane = tid & 63;
    const int wr = wid >> 1, wc = wid & 1;
    const int row0 = blockIdx.y * 128, col0 = blockIdx.x * 128;

    f32x4 acc[4][4] = {};

    const int c0 = wid * 128 + lane;
    const int c1 = c0 + 64;
    const u16* Abase = A + (size_t)row0 * K;
    const u16* Bbase = Bt + (size_t)col0 * K;

    const int gsl8 = (((lane & 3) ^ ((lane >> 3) & 3)) << 3);
    const int kg = lane >> 4, r16 = lane & 15;
    const int sl8 = ((kg ^ ((r16 >> 1) & 3)) << 3);

#define STAGE(bi, kk) do {                                                                   \
        gload_lds16(Abase + (size_t)(c0 >> 2) * K + (kk) + gsl8, &As[bi][wid * 1024]);       \
        gload_lds16(Abase + (size_t)(c1 >> 2) * K + (kk) + gsl8, &As[bi][wid * 1024 + 512]); \
        gload_lds16(Bbase + (size_t)(c0 >> 2) * K + (kk) + gsl8, &Bs[bi][wid * 1024]);       \
        gload_lds16(Bbase + (size_t)(c1 >> 2) * K + (kk) + gsl8, &Bs[bi][wid * 1024 + 512]); \
    } while (0)

    const int nt = K >> 5;
    STAGE(0, 0);
    STAGE(1, 32);
    int cs = 0;
    for (int t = 0; t < nt; ++t) {
        if (t + 2 < nt) {
            const int ss = (cs + 2 >= 3) ? cs - 1 : cs + 2;
            STAGE(ss, (t + 2) << 5);
            asm volatile("s_waitcnt vmcnt(8)" ::: "memory");
        } else if (t + 1 < nt) {
            asm volatile("s_waitcnt vmcnt(4)" ::: "memory");
        } else {
            asm volatile("s_waitcnt vmcnt(0)" ::: "memory");
        }
        __builtin_amdgcn_s_barrier();

        short8 af[4], bg[4];
#pragma unroll
        for (int i = 0; i < 4; i++) {
            const int r = wr * 64 + i * 16 + r16;
            af[i] = *(const short8*)&As[cs][r * 32 + sl8];
        }
#pragma unroll
        for (int j = 0; j < 4; j++) {
            const int r = wc * 64 + j * 16 + r16;
            bg[j] = *(const short8*)&Bs[cs][r * 32 + sl8];
        }
        __builtin_amdgcn_s_setprio(1);
#pragma unroll
        for (int i = 0; i < 4; i++)
#pragma unroll
            for (int j = 0; j < 4; j++)
                acc[i][j] = __builtin_amdgcn_mfma_f32_16x16x32_bf16(af[i], bg[j], acc[i][j], 0, 0, 0);
        __builtin_amdgcn_s_setprio(0);

        asm volatile("s_waitcnt lgkmcnt(0)" ::: "memory");
        __builtin_amdgcn_s_barrier();
        cs = (cs + 1 >= 3) ? 0 : cs + 1;
    }
#undef STAGE

#pragma unroll
    for (int i = 0; i < 4; i++) {
#pragma unroll
        for (int j = 0; j < 4; j++) {
#pragma unroll
            for (int r = 0; r < 4; r++) {
                const int row = row0 + wr * 64 + i * 16 + kg * 4 + r;
                const int col = col0 + wc * 64 + j * 16 + r16;
                const float v = acc[i][j][r] + bias[col];
                out0[(size_t)row * N + col] = v + aux[(size_t)row * N + col];
            }
        }
    }
}

// ---------------------------------------------------------------------------
// Depthwise causal conv1d (+bias) + silu, 8 channels/thread.
// ---------------------------------------------------------------------------
__global__ __launch_bounds__(256)
void conv_silu8_kernel(const u16* __restrict__ xi, const float* __restrict__ w,
                       const float* __restrict__ cb, u16* __restrict__ xcb, int total8)
{
    const int i = blockIdx.x * 256 + threadIdx.x;
    if (i >= total8) return;
    const size_t i8 = (size_t)i * 8;
    const int d8 = (int)(i8 & (D_INNER - 1));
    const int l = (int)((i8 >> 11) & 1023);

    float acc[8];
#pragma unroll
    for (int c = 0; c < 8; c++) acc[c] = cb[d8 + c];

    float4 wv[8];
#pragma unroll
    for (int c = 0; c < 8; c++) wv[c] = *(const float4*)&w[(d8 + c) * 4];

#pragma unroll
    for (int k = 0; k < D_CONV; k++) {
        if (l + k - (D_CONV - 1) >= 0) {
            const u16x8 v = *(const u16x8*)&xi[i8 + (size_t)(k - (D_CONV - 1)) * D_INNER];
#pragma unroll
            for (int c = 0; c < 8; c++) {
                const float wk = ((const float*)&wv[c])[k];
                acc[c] = fmaf(wk, bf2f(v[c]), acc[c]);
            }
        }
    }
    u16x8 o;
#pragma unroll
    for (int c = 0; c < 8; c++) o[c] = f2bf(silu_f(acc[c]));
    *(u16x8*)&xcb[i8] = o;
}

// ---------------------------------------------------------------------------
// x_proj as tiny MFMA GEMM: bc(BL x 32) = xcbf(BL x 2048) @ WxpT(32 x 2048)^T
// ---------------------------------------------------------------------------
__global__ __launch_bounds__(256)
void xproj_mfma_kernel(const u16* __restrict__ A, const u16* __restrict__ Wt,
                       const float* __restrict__ bxp, float* __restrict__ bc)
{
    const int wid = threadIdx.x >> 6, lane = threadIdx.x & 63;
    const int kg = lane >> 4, r16 = lane & 15;
    const int tok0 = blockIdx.x * 64 + wid * 16;

    f32x4 acc[2] = {};
#pragma unroll 4
    for (int k0 = 0; k0 < D_INNER; k0 += 32) {
        const short8 a  = *(const short8*)&A[(size_t)(tok0 + r16) * D_INNER + k0 + kg * 8];
        const short8 b0 = *(const short8*)&Wt[(size_t)r16 * D_INNER + k0 + kg * 8];
        const short8 b1 = *(const short8*)&Wt[(size_t)(16 + r16) * D_INNER + k0 + kg * 8];
        acc[0] = __builtin_amdgcn_mfma_f32_16x16x32_bf16(a, b0, acc[0], 0, 0, 0);
        acc[1] = __builtin_amdgcn_mfma_f32_16x16x32_bf16(a, b1, acc[1], 0, 0, 0);
    }
#pragma unroll
    for (int j = 0; j < 2; j++)
#pragma unroll
        for (int r = 0; r < 4; r++) {
            const int token = tok0 + kg * 4 + r;
            const int c = j * 16 + r16;
            bc[(size_t)token * 32 + c] = acc[j][r] + bxp[c];
        }
}

// ---------------------------------------------------------------------------
// SSM scan phase 1 (lane=channel, bf16 dt): chunk-local end state + dt-sum.
// ---------------------------------------------------------------------------
__global__ __launch_bounds__(256)
void ssm_s1_kernel(const u16* __restrict__ xcbf, const u16* __restrict__ dtbf,
                   const float* __restrict__ bc, const float* __restrict__ A_log,
                   float* __restrict__ hend, float* __restrict__ dtsum)
{
    const int tid = threadIdx.x;
    const int d = blockIdx.x * 256 + tid;
    const int c = blockIdx.y;
    const int b = blockIdx.z;

    __shared__ float sB[LCHUNK][16];
    {
        if (tid < LCHUNK * 4) {
            const int row = tid >> 2, c4 = (tid & 3) << 2;
            *(float4*)&sB[row][c4] = *(const float4*)&bc[((size_t)(b * 1024 + c * LCHUNK + row)) * 32 + c4];
        }
    }

    float Aln[D_STATE];
#pragma unroll
    for (int q = 0; q < 4; q++) {
        const f32x4 a = *(const f32x4*)&A_log[(size_t)d * D_STATE + q * 4];
        Aln[q * 4 + 0] = -__expf(a.x); Aln[q * 4 + 1] = -__expf(a.y);
        Aln[q * 4 + 2] = -__expf(a.z); Aln[q * 4 + 3] = -__expf(a.w);
    }

    const size_t base = ((size_t)(b * 1024 + c * LCHUNK)) * D_INNER + d;
    const u16* dtp = dtbf + base;
    const u16* xp = xcbf + base;

    float h[D_STATE] = {};
    float S = 0.f;
    __syncthreads();

#pragma unroll 16
    for (int j = 0; j < LCHUNK; j++) {
        const float dtf = bf2f(dtp[(size_t)j * D_INNER]);
        const float xf = bf2f(xp[(size_t)j * D_INNER]);
        const float dtx = dtf * xf;
        S += dtf;
#pragma unroll
        for (int n = 0; n < D_STATE; n++) {
            const float a = __expf(dtf * Aln[n]);
            h[n] = fmaf(a, h[n], dtx * sB[j][n]);
        }
    }

    const size_t ob = ((size_t)(b * NCHUNK + c) * D_INNER + d);
#pragma unroll
    for (int q = 0; q < 4; q++) {
        f32x4 hv = {h[q * 4 + 0], h[q * 4 + 1], h[q * 4 + 2], h[q * 4 + 3]};
        *(f32x4*)&hend[ob * D_STATE + q * 4] = hv;
    }
    dtsum[ob] = S;
}

// ---------------------------------------------------------------------------
// SSM scan phase 2: serial prefix over chunks. Thread per (d, n).
// ---------------------------------------------------------------------------
__global__ __launch_bounds__(256)
void ssm_s2_kernel(const float* __restrict__ hend, const float* __restrict__ dtsum,
                   const float* __restrict__ A_log, float* __restrict__ hin)
{
    const int tid = threadIdx.x;
    const int d = blockIdx.x * 16 + (tid >> 4);
    const int n = tid & 15;
    const int b = blockIdx.y;

    const float Aln = -__expf(A_log[(size_t)d * D_STATE + n]);
    float h = 0.f;
#pragma unroll
    for (int c = 0; c < NCHUNK; c++) {
        const size_t ob = ((size_t)(b * NCHUNK + c) * D_INNER + d);
        hin[ob * D_STATE + n] = h;
        const float P = __expf(Aln * dtsum[ob]);
        h = fmaf(P, h, hend[ob * D_STATE + n]);
    }
}

// ---------------------------------------------------------------------------
// SSM scan phase 3 (lane=channel, bf16 dt): rerun recurrence, emit y (bf16).
// ---------------------------------------------------------------------------
__global__ __launch_bounds__(256)
void ssm_s3_kernel(const u16* __restrict__ xcbf, const u16* __restrict__ dtbf,
                   const float* __restrict__ bc, const float* __restrict__ A_log,
                   const float* __restrict__ Dp, const u16* __restrict__ resbf,
                   const float* __restrict__ hin, u16* __restrict__ ybf)
{
    const int tid = threadIdx.x;
    const int d = blockIdx.x * 256 + tid;
    const int c = blockIdx.y;
    const int b = blockIdx.z;

    __shared__ float sbc[LCHUNK][32];
    {
        const int row = tid >> 3, c4 = (tid & 7) << 2;
        if (row < LCHUNK)
            *(float4*)&sbc[row][c4] = *(const float4*)&bc[((size_t)(b * 1024 + c * LCHUNK + row)) * 32 + c4];
    }

    float Aln[D_STATE];
#pragma unroll
    for (int q = 0; q < 4; q++) {
        const f32x4 a = *(const f32x4*)&A_log[(size_t)d * D_STATE + q * 4];
        Aln[q * 4 + 0] = -__expf(a.x); Aln[q * 4 + 1] = -__expf(a.y);
        Aln[q * 4 + 2] = -__expf(a.z); Aln[q * 4 + 3] = -__expf(a.w);
    }
    const float Dv = Dp[d];

    float h[D_STATE];
    const size_t ob = ((size_t)(b * NCHUNK + c) * D_INNER + d);
#pragma unroll
    for (int q = 0; q < 4; q++) {
        const f32x4 hv = *(const f32x4*)&hin[ob * D_STATE + q * 4];
        h[q * 4 + 0] = hv.x; h[q * 4 + 1] = hv.y; h[q * 4 + 2] = hv.z; h[q * 4 + 3] = hv.w;
    }

    const size_t base = ((size_t)(b * 1024 + c * LCHUNK)) * D_INNER + d;
    const u16* dtp = dtbf + base;
    const u16* xp = xcbf + base;
    const u16* rp = resbf + base;
    u16* yp = ybf + base;

    __syncthreads();

#pragma unroll 16
    for (int j = 0; j < LCHUNK; j++) {
        const float dtf = bf2f(dtp[(size_t)j * D_INNER]);
        const float xf = bf2f(xp[(size_t)j * D_INNER]);
        const float rf = bf2f(rp[(size_t)j * D_INNER]);
        const float dtx = dtf * xf;
        float yv = 0.f;
#pragma unroll
        for (int n = 0; n < D_STATE; n++) {
            const float a = __expf(dtf * Aln[n]);
            h[n] = fmaf(a, h[n], dtx * sbc[j][n]);
            yv = fmaf(h[n], sbc[j][16 + n], yv);
        }
        yv = (yv + xf * Dv) * silu_f(rf);
        yp[(size_t)j * D_INNER] = f2bf(yv);
    }
}

// ---------------------------------------------------------------------------
// LayerNorm over D_MODEL=1024 per row.
// ---------------------------------------------------------------------------
__global__ __launch_bounds__(256)
void layernorm_kernel(const float* __restrict__ z, const float* __restrict__ g,
                      const float* __restrict__ beta, float* __restrict__ out)
{
    const int row = blockIdx.x;
    const int tid = threadIdx.x;
    const float* zr = z + (size_t)row * D_MODEL;
    const float4 v = *(const float4*)&zr[tid << 2];
    float s = v.x + v.y + v.z + v.w;
    float ss = v.x * v.x + v.y * v.y + v.z * v.z + v.w * v.w;

    __shared__ float sm[256], sq[256];
    sm[tid] = s; sq[tid] = ss;
    __syncthreads();
    for (int off = 128; off > 0; off >>= 1) {
        if (tid < off) { sm[tid] += sm[tid + off]; sq[tid] += sq[tid + off]; }
        __syncthreads();
    }
    const float mean = sm[0] * (1.f / D_MODEL);
    const float var = sq[0] * (1.f / D_MODEL) - mean * mean;
    const float rstd = rsqrtf(var + 1e-5f);

    float4 o;
    o.x = (v.x - mean) * rstd * g[(tid << 2) + 0] + beta[(tid << 2) + 0];
    o.y = (v.y - mean) * rstd * g[(tid << 2) + 1] + beta[(tid << 2) + 1];
    o.z = (v.z - mean) * rstd * g[(tid << 2) + 2] + beta[(tid << 2) + 2];
    o.w = (v.w - mean) * rstd * g[(tid << 2) + 3] + beta[(tid << 2) + 3];
    *(float4*)&out[(size_t)row * D_MODEL + (tid << 2)] = o;
}

// ---------------------------------------------------------------------------
extern "C" void kernel_launch(void* const* d_in, const int* in_sizes, int n_in,
                              void* d_out, int out_size, void* d_ws, size_t ws_size,
                              hipStream_t stream)
{
    const float* x      = (const float*)d_in[0];
    const float* W_in   = (const float*)d_in[1];
    const float* b_in   = (const float*)d_in[2];
    const float* conv_w = (const float*)d_in[3];
    const float* conv_b = (const float*)d_in[4];
    const float* W_xp   = (const float*)d_in[5];
    const float* b_xp   = (const float*)d_in[6];
    const float* W_dt   = (const float*)d_in[7];
    const float* b_dt   = (const float*)d_in[8];
    const float* A_log  = (const float*)d_in[9];
    const float* D_par  = (const float*)d_in[10];
    const float* W_out  = (const float*)d_in[11];
    const float* b_out  = (const float*)d_in[12];
    const float* ln_g   = (const float*)d_in[13];
    const float* ln_b   = (const float*)d_in[14];
    float* out = (float*)d_out;

    const int BL = in_sizes[0] / D_MODEL;   // 4096
    const int Bb = BL / 1024;               // 4
    const size_t BLD = (size_t)BL * D_INNER;

    // workspace layout
    float* ws    = (float*)d_ws;
    float* bcbuf = ws;                                    // BL*32
    float* hend  = bcbuf + (size_t)BL * 32;               // 16 MB ; later zbuf
    float* dtsum = hend + (size_t)Bb * NCHUNK * D_INNER * D_STATE;  // 1 MB
    float* hinb  = dtsum + (size_t)Bb * NCHUNK * D_INNER; // 16 MB
    u16*   xibf  = (u16*)(hinb + (size_t)Bb * NCHUNK * D_INNER * D_STATE); // BLD ; later ybf
    u16*   resbf = xibf + BLD;                            // BLD
    u16*   xcbf  = resbf + BLD;                           // BLD
    u16*   dtbf  = xcbf + BLD;                            // BLD (bf16 dt)
    u16*   xbf   = dtbf + BLD;                            // BL*1024
    u16*   wxpT  = xbf + (size_t)BL * D_MODEL;            // 32*2048
    u16*   wtmp  = wxpT + 32 * D_INNER;                   // up to 4M u16
    u16*   ybf   = xibf;
    float* zbuf  = hend;                                  // hend dead after s2

    // 1) x -> bf16
    f32_to_bf16_kernel<<<(BL * D_MODEL / 4 + 255) / 256, 256, 0, stream>>>(x, xbf, BL * D_MODEL / 4);

    // 2) W_in (1024x4096) -> Wt bf16 (4096x1024)
    transpose_bf16_kernel<<<dim3(2 * D_INNER / 32, D_MODEL / 32), 256, 0, stream>>>(W_in, wtmp, D_MODEL, 2 * D_INNER);

    // 3) in_proj GEMM (8-phase 256^2): silu + gate halves (bf16)
    gemm_8ph<0><<<dim3(2 * D_INNER / 256, BL / 256), 512, 0, stream>>>(
        xbf, wtmp, b_in, xibf, resbf, BL, 2 * D_INNER, D_MODEL);

    // 4) W_xp (2048x32) -> WxpT bf16 (32x2048)
    transpose_bf16_kernel<<<dim3(1, D_INNER / 32), 256, 0, stream>>>(W_xp, wxpT, D_INNER, 32);

    // 5) depthwise causal conv + silu (bf16 in, bf16 out, 8-wide)
    conv_silu8_kernel<<<(int)(BLD / 8 / 256), 256, 0, stream>>>(
        xibf, conv_w, conv_b, xcbf, (int)(BLD / 8));

    // 6) x_proj -> B,C via MFMA (f32 out)
    xproj_mfma_kernel<<<BL / 64, 256, 0, stream>>>(xcbf, wxpT, b_xp, bcbuf);

    // 7) W_dt (2048x2048) -> Wt bf16
    transpose_bf16_kernel<<<dim3(D_INNER / 32, D_INNER / 32), 256, 0, stream>>>(W_dt, wtmp, D_INNER, D_INNER);

    // 8) dt_proj GEMM (8-phase 256^2) + softplus (bf16 out)
    gemm_8ph<1><<<dim3(D_INNER / 256, BL / 256), 512, 0, stream>>>(
        xcbf, wtmp, b_dt, dtbf, nullptr, BL, D_INNER, D_INNER);

    // 9a) scan s1: chunk-local end states + dt sums (32 chunks of 32)
    ssm_s1_kernel<<<dim3(D_INNER / 256, NCHUNK, Bb), 256, 0, stream>>>(
        xcbf, dtbf, bcbuf, A_log, hend, dtsum);

    // 9b) scan s2: prefix-combine across chunks
    ssm_s2_kernel<<<dim3(D_INNER / 16, Bb), 256, 0, stream>>>(
        hend, dtsum, A_log, hinb);

    // 9c) scan s3: rerun + emit y (bf16)
    ssm_s3_kernel<<<dim3(D_INNER / 256, NCHUNK, Bb), 256, 0, stream>>>(
        xcbf, dtbf, bcbuf, A_log, D_par, resbf, hinb, ybf);

    // 10) W_out (2048x1024) -> Wt bf16
    transpose_bf16_kernel<<<dim3(D_MODEL / 32, D_INNER / 32), 256, 0, stream>>>(W_out, wtmp, D_INNER, D_MODEL);

    // 11) out_proj GEMM (128^2) + bias + residual (f32 out to zbuf=hend)
    gemm_mfma_128<<<dim3(D_MODEL / 128, BL / 128), 256, 0, stream>>>(
        ybf, wtmp, b_out, x, zbuf, BL, D_MODEL, D_INNER);

    // 12) LayerNorm
    layernorm_kernel<<<BL, 256, 0, stream>>>(zbuf, ln_g, ln_b, out);
}

// Round 15
// 324.555 us; speedup vs baseline: 2.5145x; 2.5145x over previous
//
#include <hip/hip_runtime.h>
#include <math.h>

#define D_MODEL 1024
#define D_INNER 2048
#define D_STATE 16
#define D_CONV  4
#define NCHUNK  32
#define LCHUNK  32

typedef unsigned short u16;
typedef __attribute__((ext_vector_type(8))) short short8;
typedef __attribute__((ext_vector_type(4))) float f32x4;
typedef __attribute__((ext_vector_type(4))) unsigned short u16x4;
typedef __attribute__((ext_vector_type(8))) unsigned short u16x8;

__device__ __forceinline__ float silu_f(float x) { return x / (1.f + __expf(-x)); }
__device__ __forceinline__ float softplus_f(float x) {
    return fmaxf(x, 0.f) + log1pf(__expf(-fabsf(x)));
}
__device__ __forceinline__ u16 f2bf(float f) {
    union { float f; unsigned u; } c; c.f = f;
    unsigned r = c.u + 0x7fffu + ((c.u >> 16) & 1u);   // RNE
    return (u16)(r >> 16);
}
__device__ __forceinline__ float bf2f(u16 v) {
    union { unsigned u; float f; } c; c.u = ((unsigned)v) << 16; return c.f;
}
__device__ __forceinline__ void gload_lds16(const void* g, void* l) {
    __builtin_amdgcn_global_load_lds((const __attribute__((address_space(1))) void*)g,
                                     (__attribute__((address_space(3))) void*)l, 16, 0, 0);
}
// XCD-bijective block swizzle: nwg % 8 == 0 for all users.
__device__ __forceinline__ int xcd_swz(int lb, int nwg) {
    return (lb & 7) * (nwg >> 3) + (lb >> 3);
}

// ---------------------------------------------------------------------------
// fp32 -> bf16 elementwise convert
// ---------------------------------------------------------------------------
__global__ __launch_bounds__(256)
void f32_to_bf16_kernel(const float* __restrict__ in, u16* __restrict__ out, int n4)
{
    const int i = blockIdx.x * 256 + threadIdx.x;
    if (i >= n4) return;
    const float4 v = *(const float4*)&in[(size_t)i * 4];
    u16x4 o; o.x = f2bf(v.x); o.y = f2bf(v.y); o.z = f2bf(v.z); o.w = f2bf(v.w);
    *(u16x4*)&out[(size_t)i * 4] = o;
}

// ---------------------------------------------------------------------------
// W[K][N] fp32 -> Wt[N][K] bf16 (32x32 LDS tiles)
// ---------------------------------------------------------------------------
__global__ __launch_bounds__(256)
void transpose_bf16_kernel(const float* __restrict__ W, u16* __restrict__ Wt, int K, int N)
{
    __shared__ float tile[32][33];
    const int tx = threadIdx.x & 31, ty = threadIdx.x >> 5;
    const int n0 = blockIdx.x * 32, k0 = blockIdx.y * 32;
#pragma unroll
    for (int q = 0; q < 4; q++)
        tile[ty + q * 8][tx] = W[(size_t)(k0 + ty + q * 8) * N + n0 + tx];
    __syncthreads();
#pragma unroll
    for (int q = 0; q < 4; q++)
        Wt[(size_t)(n0 + ty + q * 8) * K + k0 + tx] = f2bf(tile[tx][ty + q * 8]);
}

// ---------------------------------------------------------------------------
// 256x256 bf16 MFMA GEMM, counted-vmcnt pipeline (proven). 8 waves, BK=64,
// wave tile 128x64. XCD-swizzled block id. MODE 0: silu/gate halves (bf16).
// ---------------------------------------------------------------------------
template <int MODE>
__global__ __launch_bounds__(512, 2)
void gemm_mfma256(const u16* __restrict__ A, const u16* __restrict__ Bt,
                  const float* __restrict__ bias,
                  void* __restrict__ out0v, void* __restrict__ out1v,
                  int M, int N, int K)
{
    __shared__ __align__(16) short As[2][256 * 64];
    __shared__ __align__(16) short Bs[2][256 * 64];

    const int tid = threadIdx.x;
    const int wid = tid >> 6, lane = tid & 63;
    const int wr = wid >> 2, wc = wid & 3;
    const int lb = xcd_swz(blockIdx.y * gridDim.x + blockIdx.x, gridDim.x * gridDim.y);
    const int row0 = (lb / gridDim.x) * 256, col0 = (lb % gridDim.x) * 256;
    const int kg = lane >> 4, r16 = lane & 15;

    f32x4 acc[8][4] = {};

    const u16* Abase = A + (size_t)row0 * K;
    const u16* Bbase = Bt + (size_t)col0 * K;

#define STAGE_A(bi, kk) do {                                                    \
        _Pragma("unroll")                                                       \
        for (int q = 0; q < 4; q++) {                                           \
            const int c = (q << 9) + tid;                                       \
            const int r = c >> 3;                                               \
            const int ks8 = (((c & 7) ^ (r & 7)) << 3);                         \
            gload_lds16(Abase + (size_t)r * K + (kk) + ks8,                     \
                        &As[bi][((q << 9) + (wid << 6)) << 3]);                 \
        }                                                                       \
    } while (0)
#define STAGE_B(bi, kk) do {                                                    \
        _Pragma("unroll")                                                       \
        for (int q = 0; q < 4; q++) {                                           \
            const int c = (q << 9) + tid;                                       \
            const int r = c >> 3;                                               \
            const int ks8 = (((c & 7) ^ (r & 7)) << 3);                         \
            gload_lds16(Bbase + (size_t)r * K + (kk) + ks8,                     \
                        &Bs[bi][((q << 9) + (wid << 6)) << 3]);                 \
        }                                                                       \
    } while (0)

    const int nt = K >> 6;
    STAGE_A(0, 0);
    STAGE_B(0, 0);

    int cur = 0;
    const int rx = r16 & 7;
    for (int t = 0; t < nt; ++t) {
        if (t + 1 < nt) {
            STAGE_A(cur ^ 1, (t + 1) << 6);
            asm volatile("s_waitcnt vmcnt(4)" ::: "memory");
        } else {
            asm volatile("s_waitcnt vmcnt(0)" ::: "memory");
        }
        __builtin_amdgcn_s_barrier();

#pragma unroll
        for (int ks = 0; ks < 2; ks++) {
            const int sl8 = (((ks << 2) + kg) ^ rx) << 3;
            short8 af[8], bg[4];
#pragma unroll
            for (int i = 0; i < 8; i++) {
                const int r = wr * 128 + i * 16 + r16;
                af[i] = *(const short8*)&As[cur][r * 64 + sl8];
            }
#pragma unroll
            for (int j = 0; j < 4; j++) {
                const int r = wc * 64 + j * 16 + r16;
                bg[j] = *(const short8*)&Bs[cur][r * 64 + sl8];
            }
            __builtin_amdgcn_s_setprio(1);
#pragma unroll
            for (int i = 0; i < 8; i++)
#pragma unroll
                for (int j = 0; j < 4; j++)
                    acc[i][j] = __builtin_amdgcn_mfma_f32_16x16x32_bf16(af[i], bg[j], acc[i][j], 0, 0, 0);
            __builtin_amdgcn_s_setprio(0);
            if (ks == 0 && t + 1 < nt)
                STAGE_B(cur ^ 1, (t + 1) << 6);
        }

        asm volatile("s_waitcnt lgkmcnt(0)" ::: "memory");
        __builtin_amdgcn_s_barrier();
        cur ^= 1;
    }
#undef STAGE_A
#undef STAGE_B

#pragma unroll
    for (int i = 0; i < 8; i++) {
#pragma unroll
        for (int j = 0; j < 4; j++) {
#pragma unroll
            for (int r = 0; r < 4; r++) {
                const int row = row0 + wr * 128 + i * 16 + kg * 4 + r;
                const int col = col0 + wc * 64 + j * 16 + r16;
                float v = acc[i][j][r] + bias[col];
                if (MODE == 0) {
                    u16* o0 = (u16*)out0v; u16* o1 = (u16*)out1v;
                    if (col < D_INNER) o0[(size_t)row * D_INNER + col] = f2bf(silu_f(v));
                    else               o1[(size_t)row * D_INNER + (col - D_INNER)] = f2bf(v);
                } else {
                    ((float*)out0v)[(size_t)row * N + col] = softplus_f(v);
                }
            }
        }
    }
}

// ---------------------------------------------------------------------------
// 128x128 bf16 MFMA GEMM (proven): triple-buffered, counted vmcnt, 4-slot
// swizzle, XCD-swizzled block id.
// MODE 1: out0(u16) = bf16(softplus(v))   MODE 2: out0(f32) = v + aux
// ---------------------------------------------------------------------------
template <int MODE>
__global__ __launch_bounds__(256)
void gemm_mfma_128(const u16* __restrict__ A, const u16* __restrict__ Bt,
                   const float* __restrict__ bias, const float* __restrict__ aux,
                   void* __restrict__ out0v, int M, int N, int K)
{
    __shared__ __align__(16) short As[3][4096];
    __shared__ __align__(16) short Bs[3][4096];

    const int tid = threadIdx.x;
    const int wid = tid >> 6, lane = tid & 63;
    const int wr = wid >> 1, wc = wid & 1;
    const int lb = xcd_swz(blockIdx.y * gridDim.x + blockIdx.x, gridDim.x * gridDim.y);
    const int row0 = (lb / gridDim.x) * 128, col0 = (lb % gridDim.x) * 128;

    f32x4 acc[4][4] = {};

    const int c0 = wid * 128 + lane;
    const int c1 = c0 + 64;
    const u16* Abase = A + (size_t)row0 * K;
    const u16* Bbase = Bt + (size_t)col0 * K;

    const int gsl8 = (((lane & 3) ^ ((lane >> 3) & 3)) << 3);
    const int kg = lane >> 4, r16 = lane & 15;
    const int sl8 = ((kg ^ ((r16 >> 1) & 3)) << 3);

#define STAGE(bi, kk) do {                                                                   \
        gload_lds16(Abase + (size_t)(c0 >> 2) * K + (kk) + gsl8, &As[bi][wid * 1024]);       \
        gload_lds16(Abase + (size_t)(c1 >> 2) * K + (kk) + gsl8, &As[bi][wid * 1024 + 512]); \
        gload_lds16(Bbase + (size_t)(c0 >> 2) * K + (kk) + gsl8, &Bs[bi][wid * 1024]);       \
        gload_lds16(Bbase + (size_t)(c1 >> 2) * K + (kk) + gsl8, &Bs[bi][wid * 1024 + 512]); \
    } while (0)

    const int nt = K >> 5;
    STAGE(0, 0);
    STAGE(1, 32);
    int cs = 0;
    for (int t = 0; t < nt; ++t) {
        if (t + 2 < nt) {
            const int ss = (cs + 2 >= 3) ? cs - 1 : cs + 2;
            STAGE(ss, (t + 2) << 5);
            asm volatile("s_waitcnt vmcnt(8)" ::: "memory");
        } else if (t + 1 < nt) {
            asm volatile("s_waitcnt vmcnt(4)" ::: "memory");
        } else {
            asm volatile("s_waitcnt vmcnt(0)" ::: "memory");
        }
        __builtin_amdgcn_s_barrier();

        short8 af[4], bg[4];
#pragma unroll
        for (int i = 0; i < 4; i++) {
            const int r = wr * 64 + i * 16 + r16;
            af[i] = *(const short8*)&As[cs][r * 32 + sl8];
        }
#pragma unroll
        for (int j = 0; j < 4; j++) {
            const int r = wc * 64 + j * 16 + r16;
            bg[j] = *(const short8*)&Bs[cs][r * 32 + sl8];
        }
        __builtin_amdgcn_s_setprio(1);
#pragma unroll
        for (int i = 0; i < 4; i++)
#pragma unroll
            for (int j = 0; j < 4; j++)
                acc[i][j] = __builtin_amdgcn_mfma_f32_16x16x32_bf16(af[i], bg[j], acc[i][j], 0, 0, 0);
        __builtin_amdgcn_s_setprio(0);

        asm volatile("s_waitcnt lgkmcnt(0)" ::: "memory");
        __builtin_amdgcn_s_barrier();
        cs = (cs + 1 >= 3) ? 0 : cs + 1;
    }
#undef STAGE

#pragma unroll
    for (int i = 0; i < 4; i++) {
#pragma unroll
        for (int j = 0; j < 4; j++) {
#pragma unroll
            for (int r = 0; r < 4; r++) {
                const int row = row0 + wr * 64 + i * 16 + kg * 4 + r;
                const int col = col0 + wc * 64 + j * 16 + r16;
                const float v = acc[i][j][r] + bias[col];
                if (MODE == 1)
                    ((u16*)out0v)[(size_t)row * N + col] = f2bf(softplus_f(v));
                else
                    ((float*)out0v)[(size_t)row * N + col] = v + aux[(size_t)row * N + col];
            }
        }
    }
}

// ---------------------------------------------------------------------------
// Depthwise causal conv1d (+bias) + silu, 8 channels/thread.
// ---------------------------------------------------------------------------
__global__ __launch_bounds__(256)
void conv_silu8_kernel(const u16* __restrict__ xi, const float* __restrict__ w,
                       const float* __restrict__ cb, u16* __restrict__ xcb, int total8)
{
    const int i = blockIdx.x * 256 + threadIdx.x;
    if (i >= total8) return;
    const size_t i8 = (size_t)i * 8;
    const int d8 = (int)(i8 & (D_INNER - 1));
    const int l = (int)((i8 >> 11) & 1023);

    float acc[8];
#pragma unroll
    for (int c = 0; c < 8; c++) acc[c] = cb[d8 + c];

    float4 wv[8];
#pragma unroll
    for (int c = 0; c < 8; c++) wv[c] = *(const float4*)&w[(d8 + c) * 4];

#pragma unroll
    for (int k = 0; k < D_CONV; k++) {
        if (l + k - (D_CONV - 1) >= 0) {
            const u16x8 v = *(const u16x8*)&xi[i8 + (size_t)(k - (D_CONV - 1)) * D_INNER];
#pragma unroll
            for (int c = 0; c < 8; c++) {
                const float wk = ((const float*)&wv[c])[k];
                acc[c] = fmaf(wk, bf2f(v[c]), acc[c]);
            }
        }
    }
    u16x8 o;
#pragma unroll
    for (int c = 0; c < 8; c++) o[c] = f2bf(silu_f(acc[c]));
    *(u16x8*)&xcb[i8] = o;
}

// ---------------------------------------------------------------------------
// x_proj as tiny MFMA GEMM: bc(BL x 32) = xcbf(BL x 2048) @ WxpT(32 x 2048)^T
// ---------------------------------------------------------------------------
__global__ __launch_bounds__(256)
void xproj_mfma_kernel(const u16* __restrict__ A, const u16* __restrict__ Wt,
                       const float* __restrict__ bxp, float* __restrict__ bc)
{
    const int wid = threadIdx.x >> 6, lane = threadIdx.x & 63;
    const int kg = lane >> 4, r16 = lane & 15;
    const int tok0 = blockIdx.x * 64 + wid * 16;

    f32x4 acc[2] = {};
#pragma unroll 4
    for (int k0 = 0; k0 < D_INNER; k0 += 32) {
        const short8 a  = *(const short8*)&A[(size_t)(tok0 + r16) * D_INNER + k0 + kg * 8];
        const short8 b0 = *(const short8*)&Wt[(size_t)r16 * D_INNER + k0 + kg * 8];
        const short8 b1 = *(const short8*)&Wt[(size_t)(16 + r16) * D_INNER + k0 + kg * 8];
        acc[0] = __builtin_amdgcn_mfma_f32_16x16x32_bf16(a, b0, acc[0], 0, 0, 0);
        acc[1] = __builtin_amdgcn_mfma_f32_16x16x32_bf16(a, b1, acc[1], 0, 0, 0);
    }
#pragma unroll
    for (int j = 0; j < 2; j++)
#pragma unroll
        for (int r = 0; r < 4; r++) {
            const int token = tok0 + kg * 4 + r;
            const int c = j * 16 + r16;
            bc[(size_t)token * 32 + c] = acc[j][r] + bxp[c];
        }
}

// ---------------------------------------------------------------------------
// SSM scan phase 1 (lane=channel, bf16 dt): chunk-local end state + dt-sum.
// ---------------------------------------------------------------------------
__global__ __launch_bounds__(256)
void ssm_s1_kernel(const u16* __restrict__ xcbf, const u16* __restrict__ dtbf,
                   const float* __restrict__ bc, const float* __restrict__ A_log,
                   float* __restrict__ hend, float* __restrict__ dtsum)
{
    const int tid = threadIdx.x;
    const int d = blockIdx.x * 256 + tid;
    const int c = blockIdx.y;
    const int b = blockIdx.z;

    __shared__ float sB[LCHUNK][16];
    {
        if (tid < LCHUNK * 4) {
            const int row = tid >> 2, c4 = (tid & 3) << 2;
            *(float4*)&sB[row][c4] = *(const float4*)&bc[((size_t)(b * 1024 + c * LCHUNK + row)) * 32 + c4];
        }
    }

    float Aln[D_STATE];
#pragma unroll
    for (int q = 0; q < 4; q++) {
        const f32x4 a = *(const f32x4*)&A_log[(size_t)d * D_STATE + q * 4];
        Aln[q * 4 + 0] = -__expf(a.x); Aln[q * 4 + 1] = -__expf(a.y);
        Aln[q * 4 + 2] = -__expf(a.z); Aln[q * 4 + 3] = -__expf(a.w);
    }

    const size_t base = ((size_t)(b * 1024 + c * LCHUNK)) * D_INNER + d;
    const u16* dtp = dtbf + base;
    const u16* xp = xcbf + base;

    float h[D_STATE] = {};
    float S = 0.f;
    __syncthreads();

#pragma unroll 16
    for (int j = 0; j < LCHUNK; j++) {
        const float dtf = bf2f(dtp[(size_t)j * D_INNER]);
        const float xf = bf2f(xp[(size_t)j * D_INNER]);
        const float dtx = dtf * xf;
        S += dtf;
#pragma unroll
        for (int n = 0; n < D_STATE; n++) {
            const float a = __expf(dtf * Aln[n]);
            h[n] = fmaf(a, h[n], dtx * sB[j][n]);
        }
    }

    const size_t ob = ((size_t)(b * NCHUNK + c) * D_INNER + d);
#pragma unroll
    for (int q = 0; q < 4; q++) {
        f32x4 hv = {h[q * 4 + 0], h[q * 4 + 1], h[q * 4 + 2], h[q * 4 + 3]};
        *(f32x4*)&hend[ob * D_STATE + q * 4] = hv;
    }
    dtsum[ob] = S;
}

// ---------------------------------------------------------------------------
// SSM scan phase 2: serial prefix over chunks. Thread per (d, n).
// ---------------------------------------------------------------------------
__global__ __launch_bounds__(256)
void ssm_s2_kernel(const float* __restrict__ hend, const float* __restrict__ dtsum,
                   const float* __restrict__ A_log, float* __restrict__ hin)
{
    const int tid = threadIdx.x;
    const int d = blockIdx.x * 16 + (tid >> 4);
    const int n = tid & 15;
    const int b = blockIdx.y;

    const float Aln = -__expf(A_log[(size_t)d * D_STATE + n]);
    float h = 0.f;
#pragma unroll
    for (int c = 0; c < NCHUNK; c++) {
        const size_t ob = ((size_t)(b * NCHUNK + c) * D_INNER + d);
        hin[ob * D_STATE + n] = h;
        const float P = __expf(Aln * dtsum[ob]);
        h = fmaf(P, h, hend[ob * D_STATE + n]);
    }
}

// ---------------------------------------------------------------------------
// SSM scan phase 3 (lane=channel, bf16 dt): rerun recurrence, emit y (bf16).
// ---------------------------------------------------------------------------
__global__ __launch_bounds__(256)
void ssm_s3_kernel(const u16* __restrict__ xcbf, const u16* __restrict__ dtbf,
                   const float* __restrict__ bc, const float* __restrict__ A_log,
                   const float* __restrict__ Dp, const u16* __restrict__ resbf,
                   const float* __restrict__ hin, u16* __restrict__ ybf)
{
    const int tid = threadIdx.x;
    const int d = blockIdx.x * 256 + tid;
    const int c = blockIdx.y;
    const int b = blockIdx.z;

    __shared__ float sbc[LCHUNK][32];
    {
        const int row = tid >> 3, c4 = (tid & 7) << 2;
        if (row < LCHUNK)
            *(float4*)&sbc[row][c4] = *(const float4*)&bc[((size_t)(b * 1024 + c * LCHUNK + row)) * 32 + c4];
    }

    float Aln[D_STATE];
#pragma unroll
    for (int q = 0; q < 4; q++) {
        const f32x4 a = *(const f32x4*)&A_log[(size_t)d * D_STATE + q * 4];
        Aln[q * 4 + 0] = -__expf(a.x); Aln[q * 4 + 1] = -__expf(a.y);
        Aln[q * 4 + 2] = -__expf(a.z); Aln[q * 4 + 3] = -__expf(a.w);
    }
    const float Dv = Dp[d];

    float h[D_STATE];
    const size_t ob = ((size_t)(b * NCHUNK + c) * D_INNER + d);
#pragma unroll
    for (int q = 0; q < 4; q++) {
        const f32x4 hv = *(const f32x4*)&hin[ob * D_STATE + q * 4];
        h[q * 4 + 0] = hv.x; h[q * 4 + 1] = hv.y; h[q * 4 + 2] = hv.z; h[q * 4 + 3] = hv.w;
    }

    const size_t base = ((size_t)(b * 1024 + c * LCHUNK)) * D_INNER + d;
    const u16* dtp = dtbf + base;
    const u16* xp = xcbf + base;
    const u16* rp = resbf + base;
    u16* yp = ybf + base;

    __syncthreads();

#pragma unroll 16
    for (int j = 0; j < LCHUNK; j++) {
        const float dtf = bf2f(dtp[(size_t)j * D_INNER]);
        const float xf = bf2f(xp[(size_t)j * D_INNER]);
        const float rf = bf2f(rp[(size_t)j * D_INNER]);
        const float dtx = dtf * xf;
        float yv = 0.f;
#pragma unroll
        for (int n = 0; n < D_STATE; n++) {
            const float a = __expf(dtf * Aln[n]);
            h[n] = fmaf(a, h[n], dtx * sbc[j][n]);
            yv = fmaf(h[n], sbc[j][16 + n], yv);
        }
        yv = (yv + xf * Dv) * silu_f(rf);
        yp[(size_t)j * D_INNER] = f2bf(yv);
    }
}

// ---------------------------------------------------------------------------
// LayerNorm over D_MODEL=1024 per row.
// ---------------------------------------------------------------------------
__global__ __launch_bounds__(256)
void layernorm_kernel(const float* __restrict__ z, const float* __restrict__ g,
                      const float* __restrict__ beta, float* __restrict__ out)
{
    const int row = blockIdx.x;
    const int tid = threadIdx.x;
    const float* zr = z + (size_t)row * D_MODEL;
    const float4 v = *(const float4*)&zr[tid << 2];
    float s = v.x + v.y + v.z + v.w;
    float ss = v.x * v.x + v.y * v.y + v.z * v.z + v.w * v.w;

    __shared__ float sm[256], sq[256];
    sm[tid] = s; sq[tid] = ss;
    __syncthreads();
    for (int off = 128; off > 0; off >>= 1) {
        if (tid < off) { sm[tid] += sm[tid + off]; sq[tid] += sq[tid + off]; }
        __syncthreads();
    }
    const float mean = sm[0] * (1.f / D_MODEL);
    const float var = sq[0] * (1.f / D_MODEL) - mean * mean;
    const float rstd = rsqrtf(var + 1e-5f);

    float4 o;
    o.x = (v.x - mean) * rstd * g[(tid << 2) + 0] + beta[(tid << 2) + 0];
    o.y = (v.y - mean) * rstd * g[(tid << 2) + 1] + beta[(tid << 2) + 1];
    o.z = (v.z - mean) * rstd * g[(tid << 2) + 2] + beta[(tid << 2) + 2];
    o.w = (v.w - mean) * rstd * g[(tid << 2) + 3] + beta[(tid << 2) + 3];
    *(float4*)&out[(size_t)row * D_MODEL + (tid << 2)] = o;
}

// ---------------------------------------------------------------------------
extern "C" void kernel_launch(void* const* d_in, const int* in_sizes, int n_in,
                              void* d_out, int out_size, void* d_ws, size_t ws_size,
                              hipStream_t stream)
{
    const float* x      = (const float*)d_in[0];
    const float* W_in   = (const float*)d_in[1];
    const float* b_in   = (const float*)d_in[2];
    const float* conv_w = (const float*)d_in[3];
    const float* conv_b = (const float*)d_in[4];
    const float* W_xp   = (const float*)d_in[5];
    const float* b_xp   = (const float*)d_in[6];
    const float* W_dt   = (const float*)d_in[7];
    const float* b_dt   = (const float*)d_in[8];
    const float* A_log  = (const float*)d_in[9];
    const float* D_par  = (const float*)d_in[10];
    const float* W_out  = (const float*)d_in[11];
    const float* b_out  = (const float*)d_in[12];
    const float* ln_g   = (const float*)d_in[13];
    const float* ln_b   = (const float*)d_in[14];
    float* out = (float*)d_out;

    const int BL = in_sizes[0] / D_MODEL;   // 4096
    const int Bb = BL / 1024;               // 4
    const size_t BLD = (size_t)BL * D_INNER;

    // workspace layout
    float* ws    = (float*)d_ws;
    float* bcbuf = ws;                                    // BL*32
    float* hend  = bcbuf + (size_t)BL * 32;               // 16 MB ; later zbuf
    float* dtsum = hend + (size_t)Bb * NCHUNK * D_INNER * D_STATE;  // 1 MB
    float* hinb  = dtsum + (size_t)Bb * NCHUNK * D_INNER; // 16 MB
    u16*   xibf  = (u16*)(hinb + (size_t)Bb * NCHUNK * D_INNER * D_STATE); // BLD ; later ybf
    u16*   resbf = xibf + BLD;                            // BLD
    u16*   xcbf  = resbf + BLD;                           // BLD
    u16*   dtbf  = xcbf + BLD;                            // BLD (bf16 dt)
    u16*   xbf   = dtbf + BLD;                            // BL*1024
    u16*   wxpT  = xbf + (size_t)BL * D_MODEL;            // 32*2048
    u16*   wtmp  = wxpT + 32 * D_INNER;                   // up to 4M u16
    u16*   ybf   = xibf;
    float* zbuf  = hend;                                  // hend dead after s2

    // 1) x -> bf16
    f32_to_bf16_kernel<<<(BL * D_MODEL / 4 + 255) / 256, 256, 0, stream>>>(x, xbf, BL * D_MODEL / 4);

    // 2) W_in (1024x4096) -> Wt bf16 (4096x1024)
    transpose_bf16_kernel<<<dim3(2 * D_INNER / 32, D_MODEL / 32), 256, 0, stream>>>(W_in, wtmp, D_MODEL, 2 * D_INNER);

    // 3) in_proj GEMM (256^2, counted-vmcnt, XCD-swizzled): silu + gate (bf16)
    gemm_mfma256<0><<<dim3(2 * D_INNER / 256, BL / 256), 512, 0, stream>>>(
        xbf, wtmp, b_in, xibf, resbf, BL, 2 * D_INNER, D_MODEL);

    // 4) W_xp (2048x32) -> WxpT bf16 (32x2048)
    transpose_bf16_kernel<<<dim3(1, D_INNER / 32), 256, 0, stream>>>(W_xp, wxpT, D_INNER, 32);

    // 5) depthwise causal conv + silu (bf16 in, bf16 out, 8-wide)
    conv_silu8_kernel<<<(int)(BLD / 8 / 256), 256, 0, stream>>>(
        xibf, conv_w, conv_b, xcbf, (int)(BLD / 8));

    // 6) x_proj -> B,C via MFMA (f32 out)
    xproj_mfma_kernel<<<BL / 64, 256, 0, stream>>>(xcbf, wxpT, b_xp, bcbuf);

    // 7) W_dt (2048x2048) -> Wt bf16
    transpose_bf16_kernel<<<dim3(D_INNER / 32, D_INNER / 32), 256, 0, stream>>>(W_dt, wtmp, D_INNER, D_INNER);

    // 8) dt_proj GEMM (128^2 triple-buffer, XCD-swizzled) + softplus (bf16 out)
    gemm_mfma_128<1><<<dim3(D_INNER / 128, BL / 128), 256, 0, stream>>>(
        xcbf, wtmp, b_dt, nullptr, dtbf, BL, D_INNER, D_INNER);

    // 9a) scan s1: chunk-local end states + dt sums (32 chunks of 32)
    ssm_s1_kernel<<<dim3(D_INNER / 256, NCHUNK, Bb), 256, 0, stream>>>(
        xcbf, dtbf, bcbuf, A_log, hend, dtsum);

    // 9b) scan s2: prefix-combine across chunks
    ssm_s2_kernel<<<dim3(D_INNER / 16, Bb), 256, 0, stream>>>(
        hend, dtsum, A_log, hinb);

    // 9c) scan s3: rerun + emit y (bf16)
    ssm_s3_kernel<<<dim3(D_INNER / 256, NCHUNK, Bb), 256, 0, stream>>>(
        xcbf, dtbf, bcbuf, A_log, D_par, resbf, hinb, ybf);

    // 10) W_out (2048x1024) -> Wt bf16
    transpose_bf16_kernel<<<dim3(D_MODEL / 32, D_INNER / 32), 256, 0, stream>>>(W_out, wtmp, D_INNER, D_MODEL);

    // 11) out_proj GEMM (128^2, XCD-swizzled) + bias + residual (f32 -> zbuf)
    gemm_mfma_128<2><<<dim3(D_MODEL / 128, BL / 128), 256, 0, stream>>>(
        ybf, wtmp, b_out, x, zbuf, BL, D_MODEL, D_INNER);

    // 12) LayerNorm
    layernorm_kernel<<<BL, 256, 0, stream>>>(zbuf, ln_g, ln_b, out);
}